// Round 3
// baseline (266.324 us; speedup 1.0000x reference)
//
#include <hip/hip_runtime.h>

typedef unsigned short u16;
typedef __attribute__((ext_vector_type(8))) short short8;
typedef __attribute__((ext_vector_type(4))) float f32x4;

#define D_TOT 2048
#define M_TOT 64
#define H_TOT 128
#define B_TOT 256
#define NG    256      /* number of d-slices (each 8 d's) */
#define XB    131072   /* D_TOT*M_TOT : x row stride per b */
#define W1M   262144   /* H_TOT*D_TOT : w1 stride per m */

__device__ __forceinline__ u16 f2bf(float f) {
  unsigned u = __builtin_bit_cast(unsigned, f);
  u = (u + 0x7fffu + ((u >> 16) & 1u)) >> 16;   // round-to-nearest-even
  return (u16)u;
}
__device__ __forceinline__ float bf2f(u16 v) {
  unsigned u = ((unsigned)v) << 16;
  return __builtin_bit_cast(float, u);
}

// ---------------------------------------------------------------------------
// phase 0: c[h] = b2[h] + sum_d b1[h,d]*w2[h,d]      grid 128 x 256
// ---------------------------------------------------------------------------
__global__ __launch_bounds__(256)
void nlm_p0(const float* __restrict__ b1, const float* __restrict__ w2,
            const float* __restrict__ b2, float* __restrict__ ch) {
  const int h = blockIdx.x, t = threadIdx.x;
  const float4* pb = (const float4*)(b1 + (size_t)h * D_TOT);
  const float4* pw = (const float4*)(w2 + (size_t)h * D_TOT);
  float s = 0.f;
  for (int i = t; i < D_TOT / 4; i += 256) {
    float4 a = pb[i], w = pw[i];
    s += a.x * w.x + a.y * w.y + a.z * w.z + a.w * w.w;
  }
  __shared__ float red[256];
  red[t] = s;
  __syncthreads();
  for (int off = 128; off > 0; off >>= 1) {
    if (t < off) red[t] += red[t + off];
    __syncthreads();
  }
  if (t == 0) ch[h] = red[0] + b2[h];
}

// ---------------------------------------------------------------------------
// fused main: per-block g (8 d's), B' slice packed DIRECTLY into LDS
// (no Bp round-trip), then 4 bq x 8 c MFMA iterations over all 256 b.
// grid 256 (1 block/CU, LDS 147 KB); block 512 = 8 waves as 2(bm) x 4(hn).
// g-swizzle: XCD k hosts g in [32k,32k+32) so the 4 g's sharing each 128-B
// w1 line are co-XCD -> w1 HBM fetch ~67 MB (line fetched once, L2 hits).
// Bs layout [c][h][m] bf16 with XOR swizzle (in-row byte ^= (h&7)<<4):
// write side and read side apply the same involution (rule #21).
// c-loop uses raw s_barrier + lgkmcnt(0) (NO vmcnt drain) so the depth-2
// x register prefetch stays in flight across barriers (T4/T14).
// Loop nest bq(runtime,4) x c(unrolled,8): prefetch-pair parity = c&1 is
// compile-time -> register pairs statically indexed (rule #20).
// ---------------------------------------------------------------------------
__global__ __launch_bounds__(512, 2)
void nlm_main(const float* __restrict__ x, const float* __restrict__ w1,
              const float* __restrict__ w2, u16* __restrict__ partial) {
  __shared__ __align__(16) u16 Bs[8 * H_TOT * 64];  // 128 KB, [c][h][m] swizzled
  __shared__ __align__(16) u16 As[2][64 * 72];      // dbuf, row b_l: 64 m + 8 pad

  const int tid  = threadIdx.x;
  const int lane = tid & 63, wave = tid >> 6;
  const int g    = ((blockIdx.x & 7) << 5) + (blockIdx.x >> 3);  // bijective, 256%8==0
  const int d0   = g * 8;

  // A staging map: thread -> (b_l = tid>>3, part = tid&7): 32 B of one x row
  const int a_bl = tid >> 3, a_p = tid & 7;
  const float* xbase = x + (size_t)a_bl * XB + (size_t)d0 * M_TOT + a_p * 8;

  // early-issue x loads for tt=0 (arrive during pack phase)
  float4 e0 = *(const float4*)(xbase);
  float4 e1 = *(const float4*)(xbase + 4);

  // ---- pack phase: Bs[c][h][m] = bf16(w1[m][h][d0+c] * w2[h][d0+c])
  // task: h = wave*16 + rep (wave-uniform -> w2 load scalarizes), m = lane.
  // w1 read = 32-B d-runs; other 96 B of each 128-B line consumed by the
  // 3 co-XCD neighbor blocks via L2.
  {
    const int m = lane;
#pragma unroll 4
    for (int rep = 0; rep < 16; ++rep) {
      const int h = wave * 16 + rep;
      const float* w1p = w1 + (size_t)m * W1M + (size_t)h * D_TOT + d0;
      const float* w2p = w2 + (size_t)h * D_TOT + d0;
      float4 a0 = *(const float4*)(w1p);
      float4 a1 = *(const float4*)(w1p + 4);
      float4 s0 = *(const float4*)(w2p);
      float4 s1 = *(const float4*)(w2p + 4);
      // byte addr = c*16384 + h*128 + ((m*2) ^ ((h&7)<<4))
      u16* dst = (u16*)((char*)Bs + h * 128 + ((m * 2) ^ ((h & 7) << 4)));
      dst[0 * 8192] = f2bf(a0.x * s0.x);
      dst[1 * 8192] = f2bf(a0.y * s0.y);
      dst[2 * 8192] = f2bf(a0.z * s0.z);
      dst[3 * 8192] = f2bf(a0.w * s0.w);
      dst[4 * 8192] = f2bf(a1.x * s1.x);
      dst[5 * 8192] = f2bf(a1.y * s1.y);
      dst[6 * 8192] = f2bf(a1.z * s1.z);
      dst[7 * 8192] = f2bf(a1.w * s1.w);
    }
  }
  __syncthreads();

  // ---- compute setup
  const int wm = wave >> 2, wn = wave & 3;
  const int quad = lane >> 4, l16 = lane & 15;
  const int q16 = quad * 16;

  int aoff[2][2];  // u16 index into an As buffer (i, s) - compile-time indexed
#pragma unroll
  for (int i = 0; i < 2; ++i)
#pragma unroll
    for (int s = 0; s < 2; ++s)
      aoff[i][s] = (wm * 32 + i * 16 + l16) * 72 + s * 32 + quad * 8;

  int boff[2][2];  // byte offset into Bs (j, s); add c*16384 per plane
#pragma unroll
  for (int j = 0; j < 2; ++j) {
    const int hr = wn * 32 + j * 16 + l16;
    const int bx = (hr & 7) << 4;
#pragma unroll
    for (int s = 0; s < 2; ++s)
      boff[j][s] = hr * 128 + ((s * 64 + q16) ^ bx);
  }

  // stage tt=0 into As[0]
  {
    short8 av;
    av[0] = (short)f2bf(e0.x); av[1] = (short)f2bf(e0.y);
    av[2] = (short)f2bf(e0.z); av[3] = (short)f2bf(e0.w);
    av[4] = (short)f2bf(e1.x); av[5] = (short)f2bf(e1.y);
    av[6] = (short)f2bf(e1.z); av[7] = (short)f2bf(e1.w);
    *(short8*)(&As[0][0] + a_bl * 72 + a_p * 8) = av;
  }
  // issue tt=1 -> pair1 (loads for iteration tt live in pair tt&1 = c&1)
  float4 p00, p01, p10, p11;
  {
    const float* xp = xbase + 1 * M_TOT;
    p10 = *(const float4*)(xp);
    p11 = *(const float4*)(xp + 4);
  }
  asm volatile("s_waitcnt lgkmcnt(0)" ::: "memory");
  __builtin_amdgcn_s_barrier();

  f32x4 acc[2][2];

  for (int bq = 0; bq < 4; ++bq) {
#pragma unroll
    for (int i = 0; i < 2; ++i)
#pragma unroll
      for (int j = 0; j < 2; ++j) acc[i][j] = (f32x4){0.f, 0.f, 0.f, 0.f};

#pragma unroll
    for (int c = 0; c < 8; ++c) {
      // ---- issue loads for tt+2 into pair (c&1) (consumed at tt-1)
      if (bq < 3 || c < 6) {
        const int bq2 = (c < 6) ? bq : bq + 1;
        const int c2  = (c < 6) ? c + 2 : c - 6;
        const float* xp = xbase + (size_t)bq2 * (64 * (size_t)XB) + c2 * M_TOT;
        if ((c & 1) == 0) { p00 = *(const float4*)(xp); p01 = *(const float4*)(xp + 4); }
        else              { p10 = *(const float4*)(xp); p11 = *(const float4*)(xp + 4); }
      }
      // ---- frag reads + MFMA on As[c&1], Bs c-plane
      {
        const u16*  Ab = &As[c & 1][0];
        const char* Bb = (const char*)Bs + c * 16384;
#pragma unroll
        for (int s = 0; s < 2; ++s) {
          short8 af0 = *(const short8*)(Ab + aoff[0][s]);
          short8 af1 = *(const short8*)(Ab + aoff[1][s]);
          short8 bf0 = *(const short8*)(Bb + boff[0][s]);
          short8 bf1 = *(const short8*)(Bb + boff[1][s]);
          acc[0][0] = __builtin_amdgcn_mfma_f32_16x16x32_bf16(af0, bf0, acc[0][0], 0, 0, 0);
          acc[0][1] = __builtin_amdgcn_mfma_f32_16x16x32_bf16(af0, bf1, acc[0][1], 0, 0, 0);
          acc[1][0] = __builtin_amdgcn_mfma_f32_16x16x32_bf16(af1, bf0, acc[1][0], 0, 0, 0);
          acc[1][1] = __builtin_amdgcn_mfma_f32_16x16x32_bf16(af1, bf1, acc[1][1], 0, 0, 0);
        }
      }
      // ---- convert + stage tt+1 into As[(c+1)&1] from pair ((c+1)&1)
      if (bq < 3 || c < 7) {
        float4 s0 = ((c + 1) & 1) ? p10 : p00;
        float4 s1 = ((c + 1) & 1) ? p11 : p01;
        short8 av;
        av[0] = (short)f2bf(s0.x); av[1] = (short)f2bf(s0.y);
        av[2] = (short)f2bf(s0.z); av[3] = (short)f2bf(s0.w);
        av[4] = (short)f2bf(s1.x); av[5] = (short)f2bf(s1.y);
        av[6] = (short)f2bf(s1.z); av[7] = (short)f2bf(s1.w);
        *(short8*)(&As[(c + 1) & 1][0] + a_bl * 72 + a_p * 8) = av;
      }
      // per-wave LDS drain, then raw barrier; NO vmcnt drain -> x prefetch
      // stays in flight across the barrier.
      asm volatile("s_waitcnt lgkmcnt(0)" ::: "memory");
      __builtin_amdgcn_s_barrier();
    }

    // ---- epilogue for this bq (registers only; no LDS hazard)
#pragma unroll
    for (int i = 0; i < 2; ++i)
#pragma unroll
      for (int j = 0; j < 2; ++j) {
        const int hcol = wn * 32 + j * 16 + l16;
#pragma unroll
        for (int r = 0; r < 4; ++r) {
          const int brow = bq * 64 + wm * 32 + i * 16 + quad * 4 + r;
          partial[((size_t)brow * NG + g) * H_TOT + hcol] = f2bf(acc[i][j][r]);
        }
      }
  }
}

// ---------------------------------------------------------------------------
// phase 2: out[b,h] = sum_g partial[b][g][h] + c[h]     grid 256 x 256
// ---------------------------------------------------------------------------
__global__ __launch_bounds__(256)
void nlm_p2(const u16* __restrict__ partial, const float* __restrict__ ch,
            float* __restrict__ out) {
  const int b = blockIdx.x, t = threadIdx.x;
  const int h2   = t & 63;    // ushort2 column: h = 2*h2, 2*h2+1
  const int half = t >> 6;    // 0..3 : g range
  const u16* base = partial + ((size_t)b * NG + half * 64) * H_TOT + 2 * h2;
  float s0 = 0.f, s1 = 0.f;
#pragma unroll 8
  for (int gg = 0; gg < 64; ++gg) {
    unsigned v = __builtin_nontemporal_load((const unsigned*)(base + (size_t)gg * H_TOT));
    s0 += bf2f((u16)(v & 0xffffu));
    s1 += bf2f((u16)(v >> 16));
  }
  __shared__ float red0[256], red1[256];
  red0[t] = s0;
  red1[t] = s1;
  __syncthreads();
  if (t < 64) {
    float a0 = red0[t] + red0[t + 64] + red0[t + 128] + red0[t + 192];
    float a1 = red1[t] + red1[t + 64] + red1[t + 128] + red1[t + 192];
    out[(size_t)b * H_TOT + 2 * t]     = a0 + ch[2 * t];
    out[(size_t)b * H_TOT + 2 * t + 1] = a1 + ch[2 * t + 1];
  }
}

// ---------------------------------------------------------------------------
extern "C" void kernel_launch(void* const* d_in, const int* in_sizes, int n_in,
                              void* d_out, int out_size, void* d_ws, size_t ws_size,
                              hipStream_t stream) {
  const float* x  = (const float*)d_in[0];
  const float* w1 = (const float*)d_in[1];
  const float* b1 = (const float*)d_in[2];
  const float* w2 = (const float*)d_in[3];
  const float* b2 = (const float*)d_in[4];
  float* out = (float*)d_out;

  // ws: partial 16.78 MB | ch 512 B
  u16*   partial = (u16*)d_ws;
  float* ch      = (float*)((char*)d_ws + (size_t)B_TOT * NG * H_TOT * sizeof(u16));

  nlm_p0<<<dim3(128),   dim3(256), 0, stream>>>(b1, w2, b2, ch);
  nlm_main<<<dim3(256), dim3(512), 0, stream>>>(x, w1, w2, partial);
  nlm_p2<<<dim3(256),   dim3(256), 0, stream>>>(partial, ch, out);
}